// Round 2
// baseline (13360.123 us; speedup 1.0000x reference)
//
#include <hip/hip_runtime.h>
#include <hip/hip_bf16.h>
#include <cstdio>

typedef unsigned short ushort_t;
typedef __attribute__((ext_vector_type(4))) float f32x4;
typedef __attribute__((ext_vector_type(4))) unsigned int u32x4;
typedef __attribute__((ext_vector_type(8))) __bf16 bf16x8;
typedef __attribute__((ext_vector_type(8))) unsigned short u16x8;
typedef __attribute__((ext_vector_type(4))) unsigned short u16x4;

#define B_  16
#define T_  1024
#define H_  512
#define NG  2048          // 4*H
#define M_  (B_*T_)       // 16384
#define NBLK_DIR 16       // lstm blocks per direction
#define FLAG_T 1056       // padded per-(layer,dir) flag rows

__device__ inline unsigned short f2bf_rne(float f){
  union { float f; unsigned int u; } v; v.f = f;
  unsigned int u = v.u;
  unsigned int r = (u + 0x7fffu + ((u >> 16) & 1u)) >> 16;
  return (unsigned short)r;
}
__device__ inline float bf2f(unsigned short s){
  union { unsigned int u; float f; } v; v.u = ((unsigned int)s) << 16;
  return v.f;
}

__global__ void zero_u32(unsigned* __restrict__ p, int n){
  int i = blockIdx.x * blockDim.x + threadIdx.x;
  if (i < n) p[i] = 0u;
}

// ---------------- split f32 -> bf16 hi + bf16 lo ----------------
__global__ void split_f32_bf16(const float* __restrict__ src,
                               ushort_t* __restrict__ hi, ushort_t* __restrict__ lo,
                               int n4){
  int i = blockIdx.x * blockDim.x + threadIdx.x;
  int stride = gridDim.x * blockDim.x;
  for (; i < n4; i += stride){
    f32x4 v = ((const f32x4*)src)[i];
    u16x4 h4, l4;
    #pragma unroll
    for (int j = 0; j < 4; j++){
      unsigned short h = f2bf_rne(v[j]);
      h4[j] = h;
      l4[j] = f2bf_rne(v[j] - bf2f(h));
    }
    ((u16x4*)hi)[i] = h4;
    ((u16x4*)lo)[i] = l4;
  }
}

// ---------------- split-bf16 MFMA GEMM: C = A * B^T + bias ----------------
// A: M x K row-major (hi/lo bf16); B: N x K row-major (w_ih layout); C: M x N f32.
// blockIdx.z = direction (separate B, bias, C).
__global__ __launch_bounds__(256) void gemm_xg(
    const ushort_t* __restrict__ Ahi, const ushort_t* __restrict__ Alo,
    const ushort_t* __restrict__ Bhi0, const ushort_t* __restrict__ Blo0,
    const ushort_t* __restrict__ Bhi1, const ushort_t* __restrict__ Blo1,
    const float* __restrict__ bi0, const float* __restrict__ bh0,
    const float* __restrict__ bi1, const float* __restrict__ bh1,
    float* __restrict__ C0, float* __restrict__ C1,
    int M, int N, int K)
{
  __shared__ ushort_t As[128*32];
  __shared__ ushort_t Bs[128*32];
  const int tid  = threadIdx.x;
  const int wave = tid >> 6, lane = tid & 63;
  const int l15 = lane & 15, l4 = lane >> 4;
  const int wr = wave >> 1, wc = wave & 1;
  const int n0 = blockIdx.x * 128, m0 = blockIdx.y * 128;
  const int dir = blockIdx.z;
  const ushort_t* Bhi = dir ? Bhi1 : Bhi0;
  const ushort_t* Blo = dir ? Blo1 : Blo0;
  const float* bia = dir ? bi1 : bi0;
  const float* bib = dir ? bh1 : bh0;
  float* C = dir ? C1 : C0;

  f32x4 acc[4][4];
  #pragma unroll
  for (int i = 0; i < 4; i++)
    #pragma unroll
    for (int j = 0; j < 4; j++) acc[i][j] = (f32x4){0.f,0.f,0.f,0.f};

  for (int seg = 0; seg < 3; ++seg){
    const ushort_t* Ap = (seg == 2) ? Alo : Ahi;
    const ushort_t* Bp = (seg == 1) ? Blo : Bhi;
    for (int kt = 0; kt < K; kt += 32){
      #pragma unroll
      for (int i = 0; i < 2; i++){
        int e = i * 256 + tid;              // 0..511 chunks of 8 bf16
        int row = e >> 2, c8 = (e & 3) * 8;
        u32x4 va = *(const u32x4*)(Ap + (size_t)(m0 + row) * K + kt + c8);
        u32x4 vb = *(const u32x4*)(Bp + (size_t)(n0 + row) * K + kt + c8);
        *(u32x4*)(As + e * 8) = va;
        *(u32x4*)(Bs + e * 8) = vb;
      }
      __syncthreads();
      bf16x8 af[4], bfr[4];
      #pragma unroll
      for (int m = 0; m < 4; m++)
        af[m] = *(const bf16x8*)(As + (wr*64 + m*16 + l15) * 32 + l4 * 8);
      #pragma unroll
      for (int n = 0; n < 4; n++)
        bfr[n] = *(const bf16x8*)(Bs + (wc*64 + n*16 + l15) * 32 + l4 * 8);
      #pragma unroll
      for (int m = 0; m < 4; m++)
        #pragma unroll
        for (int n = 0; n < 4; n++)
          acc[m][n] = __builtin_amdgcn_mfma_f32_16x16x32_bf16(af[m], bfr[n], acc[m][n], 0, 0, 0);
      __syncthreads();
    }
  }
  #pragma unroll
  for (int m = 0; m < 4; m++)
    #pragma unroll
    for (int n = 0; n < 4; n++){
      int col = n0 + wc*64 + n*16 + l15;
      float bias = bia[col] + bib[col];
      #pragma unroll
      for (int r = 0; r < 4; r++){
        int row = m0 + wr*64 + m*16 + l4*4 + r;
        C[(size_t)row * N + col] = acc[m][n][r] + bias;
      }
    }
}

// ---------------- persistent bidirectional LSTM layer (flag-sync) ----------------
// 32 blocks x 512 threads. Block = (dir = blk>>4, cb = blk&15), owns h-cols [32*cb, 32*cb+32).
// Wave = (gate = w>>1, colhalf = w&1). W_hh split-bf16 in registers.
// Sync: per-step monotonic flags (release/acquire, agent scope), no grid barrier.
__global__ __launch_bounds__(512, 1) void lstm_layer(
    const float* __restrict__ whh_fwd, const float* __restrict__ whh_bwd,
    const float* __restrict__ xg,      // [2][M_][NG], m = b*T + t
    ushort_t* __restrict__ h_ex,       // [2 dir][2 buf][2 hi/lo][16][512]
    float* __restrict__ out_f32,       // [B][T][1024] or null
    ushort_t* __restrict__ out_hi,     // [B][T][1024] or null (split output)
    ushort_t* __restrict__ out_lo,
    unsigned* __restrict__ flags)      // [2 dir][FLAG_T][16]
{
  const int dir = blockIdx.x >> 4;
  const int cb  = blockIdx.x & 15;
  const int tid = threadIdx.x;
  const int wave = tid >> 6, lane = tid & 63;
  const int gate = wave >> 1, ch = wave & 1;
  const int l15 = lane & 15, l4 = lane >> 4;
  const float* whh = dir ? whh_bwd : whh_fwd;
  unsigned* fl = flags + (size_t)dir * FLAG_T * 16;

  __shared__ ushort_t hhi[16][528];   // row stride 1056B: 16B-aligned
  __shared__ ushort_t hlo[16][528];
  __shared__ float gbuf[4][16][33];
  __shared__ float cst[16][33];

  // --- W_hh fragments (split bf16): wave rows gate*512 + cb*32 + ch*16 + l15 ---
  bf16x8 Whi[16], Wlo[16];
  {
    const int wrow = gate * 512 + cb * 32 + ch * 16 + l15;
    const float* p0 = whh + (size_t)wrow * 512;
    #pragma unroll
    for (int s = 0; s < 16; s++){
      const float* p = p0 + s * 32 + l4 * 8;
      f32x4 va = *(const f32x4*)(p);
      f32x4 vb = *(const f32x4*)(p + 4);
      u16x8 th, tl;
      #pragma unroll
      for (int j = 0; j < 4; j++){
        unsigned short h = f2bf_rne(va[j]);
        th[j] = h; tl[j] = f2bf_rne(va[j] - bf2f(h));
        unsigned short h2 = f2bf_rne(vb[j]);
        th[4+j] = h2; tl[4+j] = f2bf_rne(vb[j] - bf2f(h2));
      }
      Whi[s] = __builtin_bit_cast(bf16x8, th);
      Wlo[s] = __builtin_bit_cast(bf16x8, tl);
    }
  }
  // --- zero h buffer 0 (own slice) + c state; publish flag[0] ---
  {
    int b = tid >> 5, cl = tid & 31;
    int col = cb * 32 + cl;
    ushort_t* base = h_ex + (size_t)dir * 2 * 2 * (16 * 512);   // buf0 hi
    base[b * 512 + col] = 0;
    base[16*512 + b * 512 + col] = 0;                            // buf0 lo
    cst[b][cl] = 0.0f;
  }
  __syncthreads();
  if (tid == 0){
    __threadfence();
    __hip_atomic_store(&fl[0 * 16 + cb], 1u, __ATOMIC_RELEASE, __HIP_MEMORY_SCOPE_AGENT);
  }

  for (int t = 0; t < T_; ++t){
    // wait for all 16 producer slices of h_t
    if (tid < NBLK_DIR){
      const unsigned* f = &fl[(size_t)t * 16 + tid];
      while (__hip_atomic_load(f, __ATOMIC_RELAXED, __HIP_MEMORY_SCOPE_AGENT) == 0u)
        __builtin_amdgcn_s_sleep(1);
    }
    if (tid == 0) __threadfence();   // acquire: invalidate L1/L2 before h loads
    __syncthreads();

    // stage h_t (hi+lo, 16x512 each) into LDS
    const ushort_t* src = h_ex + ((size_t)dir * 2 + (t & 1)) * 2 * (16 * 512);
    #pragma unroll
    for (int i = 0; i < 4; i++){
      int q = i * 512 + tid;              // 0..2047 chunks of 8
      int mat = q >> 10;
      int row = (q >> 6) & 15;
      int c8  = (q & 63) * 8;
      u32x4 v = *(const u32x4*)(src + mat * (16*512) + row * 512 + c8);
      ushort_t* dst = mat ? &hlo[row][c8] : &hhi[row][c8];
      *(u32x4*)dst = v;
    }
    __syncthreads();

    // gates: acc[m=batch][n=own 16 cols] over K=512 (3 split terms)
    f32x4 acc = {0.f,0.f,0.f,0.f};
    #pragma unroll
    for (int s = 0; s < 16; s++){
      bf16x8 a = *(const bf16x8*)(&hhi[l15][s * 32 + l4 * 8]);
      acc = __builtin_amdgcn_mfma_f32_16x16x32_bf16(a, Whi[s], acc, 0, 0, 0);
    }
    #pragma unroll
    for (int s = 0; s < 16; s++){
      bf16x8 a = *(const bf16x8*)(&hhi[l15][s * 32 + l4 * 8]);
      acc = __builtin_amdgcn_mfma_f32_16x16x32_bf16(a, Wlo[s], acc, 0, 0, 0);
    }
    #pragma unroll
    for (int s = 0; s < 16; s++){
      bf16x8 a = *(const bf16x8*)(&hlo[l15][s * 32 + l4 * 8]);
      acc = __builtin_amdgcn_mfma_f32_16x16x32_bf16(a, Whi[s], acc, 0, 0, 0);
    }
    #pragma unroll
    for (int r = 0; r < 4; r++)
      gbuf[gate][l4 * 4 + r][ch * 16 + l15] = acc[r];
    __syncthreads();

    // elementwise: 512 threads = 16 batch x 32 cols
    {
      int b = tid >> 5, cl = tid & 31;
      int col = cb * 32 + cl;
      int t_eff = dir ? (T_ - 1 - t) : t;
      const float* xgp = xg + ((size_t)dir * M_ + (size_t)b * T_ + t_eff) * NG + col;
      float pi = gbuf[0][b][cl] + xgp[0 * 512];
      float pf = gbuf[1][b][cl] + xgp[1 * 512];
      float pg = gbuf[2][b][cl] + xgp[2 * 512];
      float po = gbuf[3][b][cl] + xgp[3 * 512];
      float ig = 1.0f / (1.0f + __expf(-pi));
      float fg = 1.0f / (1.0f + __expf(-pf));
      float gg = tanhf(pg);
      float og = 1.0f / (1.0f + __expf(-po));
      float c  = fg * cst[b][cl] + ig * gg;
      cst[b][cl] = c;
      float h = og * tanhf(c);
      size_t oidx = ((size_t)b * T_ + t_eff) * 1024 + dir * 512 + col;
      unsigned short hh = f2bf_rne(h);
      unsigned short hl = f2bf_rne(h - bf2f(hh));
      if (out_f32) out_f32[oidx] = h;
      if (out_hi){ out_hi[oidx] = hh; out_lo[oidx] = hl; }
      ushort_t* nb = h_ex + ((size_t)dir * 2 + ((t + 1) & 1)) * 2 * (16 * 512);
      nb[b * 512 + col] = hh;
      nb[16*512 + b * 512 + col] = hl;
    }
    __syncthreads();
    if (tid == 0){
      __threadfence();   // release: write back XCD L2 before publishing
      __hip_atomic_store(&fl[(size_t)(t + 1) * 16 + cb], 1u, __ATOMIC_RELEASE, __HIP_MEMORY_SCOPE_AGENT);
    }
  }
}

// ---------------- attention pooling ----------------
__device__ inline float dot4(f32x4 a, f32x4 b){
  return a[0]*b[0] + a[1]*b[1] + a[2]*b[2] + a[3]*b[3];
}

__global__ __launch_bounds__(256) void attn_pool(
    const float* __restrict__ out1,   // [B][T][1024]
    const float* __restrict__ aw,     // [1024]
    const float* __restrict__ ab,     // [1]
    float* __restrict__ enc)          // [B][1024]
{
  __shared__ float wbuf[1024];
  __shared__ float sc[1024];
  __shared__ float red[16];
  const int b = blockIdx.x;
  const int tid = threadIdx.x;
  const int wave = tid >> 6, lane = tid & 63;
  ((f32x4*)wbuf)[tid] = ((const f32x4*)aw)[tid];
  __syncthreads();
  const float* ob = out1 + (size_t)b * T_ * 1024;
  const float bias = ab[0];

  // scores: wave-per-row, coalesced
  for (int t = wave; t < T_; t += 4){
    const float* row = ob + (size_t)t * 1024;
    float s = dot4(((const f32x4*)row)[lane],       ((const f32x4*)wbuf)[lane])
            + dot4(((const f32x4*)row)[lane + 64],  ((const f32x4*)wbuf)[lane + 64])
            + dot4(((const f32x4*)row)[lane + 128], ((const f32x4*)wbuf)[lane + 128])
            + dot4(((const f32x4*)row)[lane + 192], ((const f32x4*)wbuf)[lane + 192]);
    #pragma unroll
    for (int o = 32; o > 0; o >>= 1) s += __shfl_xor(s, o, 64);
    if (lane == 0) sc[t] = s + bias;
  }
  __syncthreads();

  float m = -1e30f;
  for (int i = tid; i < 1024; i += 256) m = fmaxf(m, sc[i]);
  #pragma unroll
  for (int o = 32; o > 0; o >>= 1) m = fmaxf(m, __shfl_xor(m, o, 64));
  if (lane == 0) red[wave] = m;
  __syncthreads();
  m = fmaxf(fmaxf(red[0], red[1]), fmaxf(red[2], red[3]));

  float ssum = 0.f;
  for (int i = tid; i < 1024; i += 256){
    float p = __expf(sc[i] - m);
    sc[i] = p;
    ssum += p;
  }
  #pragma unroll
  for (int o = 32; o > 0; o >>= 1) ssum += __shfl_xor(ssum, o, 64);
  if (lane == 0) red[8 + wave] = ssum;
  __syncthreads();
  float inv = 1.0f / (red[8] + red[9] + red[10] + red[11]);

  f32x4 a = {0.f,0.f,0.f,0.f};
  for (int t = 0; t < T_; t++){
    f32x4 v = *(const f32x4*)(ob + (size_t)t * 1024 + tid * 4);
    float p = sc[t];
    a[0] += p * v[0]; a[1] += p * v[1]; a[2] += p * v[2]; a[3] += p * v[3];
  }
  f32x4 r = { a[0]*inv, a[1]*inv, a[2]*inv, a[3]*inv };
  *(f32x4*)(enc + (size_t)b * 1024 + tid * 4) = r;
}

// ---------------- host ----------------
extern "C" void kernel_launch(void* const* d_in, const int* in_sizes, int n_in,
                              void* d_out, int out_size, void* d_ws, size_t ws_size,
                              hipStream_t stream)
{
  const float* x        = (const float*)d_in[0];
  const float* w_ih_l0  = (const float*)d_in[1];
  const float* w_hh_l0  = (const float*)d_in[2];
  const float* b_ih_l0  = (const float*)d_in[3];
  const float* b_hh_l0  = (const float*)d_in[4];
  const float* w_ih_l0r = (const float*)d_in[5];
  const float* w_hh_l0r = (const float*)d_in[6];
  const float* b_ih_l0r = (const float*)d_in[7];
  const float* b_hh_l0r = (const float*)d_in[8];
  const float* w_ih_l1  = (const float*)d_in[9];
  const float* w_hh_l1  = (const float*)d_in[10];
  const float* b_ih_l1  = (const float*)d_in[11];
  const float* b_hh_l1  = (const float*)d_in[12];
  const float* w_ih_l1r = (const float*)d_in[13];
  const float* w_hh_l1r = (const float*)d_in[14];
  const float* b_ih_l1r = (const float*)d_in[15];
  const float* b_hh_l1r = (const float*)d_in[16];
  const float* attn_w   = (const float*)d_in[17];
  const float* attn_b   = (const float*)d_in[18];
  float* enc = (float*)d_out;

  char* ws = (char*)d_ws;
  size_t off = 0;
  auto alloc = [&](size_t bytes) -> void* {
    void* p = ws + off;
    off += (bytes + 255) & ~(size_t)255;
    return p;
  };
  ushort_t* Ahi  = (ushort_t*)alloc((size_t)M_ * 2048 * 2);
  ushort_t* Alo  = (ushort_t*)alloc((size_t)M_ * 2048 * 2);
  ushort_t* Whi0 = (ushort_t*)alloc((size_t)2048 * 2048 * 2);
  ushort_t* Wlo0 = (ushort_t*)alloc((size_t)2048 * 2048 * 2);
  ushort_t* Whi1 = (ushort_t*)alloc((size_t)2048 * 2048 * 2);
  ushort_t* Wlo1 = (ushort_t*)alloc((size_t)2048 * 2048 * 2);
  float*    xg   = (float*)alloc((size_t)2 * M_ * NG * 4);
  float*    outb = (float*)alloc((size_t)M_ * 1024 * 4);
  ushort_t* h_ex = (ushort_t*)alloc((size_t)2 * 2 * 2 * 16 * 512 * 2);
  unsigned* flags= (unsigned*)alloc((size_t)4 * FLAG_T * 16 * 4);   // [layer][dir][t][blk]
  if (off > ws_size){
    fprintf(stderr, "kernel_launch: workspace too small: need %zu have %zu\n", off, ws_size);
    return;
  }

  // zero all flags (monotonic handshake state) every call — replay-deterministic
  {
    int n = 4 * FLAG_T * 16;
    zero_u32<<<(n + 255) / 256, 256, 0, stream>>>(flags, n);
  }

  // ---- layer 0 ----
  split_f32_bf16<<<2048, 256, 0, stream>>>(x, Ahi, Alo, M_ * 2048 / 4);
  split_f32_bf16<<<512, 256, 0, stream>>>(w_ih_l0,  Whi0, Wlo0, 2048 * 2048 / 4);
  split_f32_bf16<<<512, 256, 0, stream>>>(w_ih_l0r, Whi1, Wlo1, 2048 * 2048 / 4);
  gemm_xg<<<dim3(16, 128, 2), 256, 0, stream>>>(
      Ahi, Alo, Whi0, Wlo0, Whi1, Wlo1,
      b_ih_l0, b_hh_l0, b_ih_l0r, b_hh_l0r,
      xg, xg + (size_t)M_ * NG, M_, NG, 2048);
  // LSTM layer 0: writes split-bf16 output directly into Ahi/Alo (x splits dead now)
  lstm_layer<<<32, 512, 0, stream>>>(w_hh_l0, w_hh_l0r, xg, h_ex,
                                     nullptr, Ahi, Alo, flags);
  // ---- layer 1 ----
  split_f32_bf16<<<512, 256, 0, stream>>>(w_ih_l1,  Whi0, Wlo0, 2048 * 1024 / 4);
  split_f32_bf16<<<512, 256, 0, stream>>>(w_ih_l1r, Whi1, Wlo1, 2048 * 1024 / 4);
  gemm_xg<<<dim3(16, 128, 2), 256, 0, stream>>>(
      Ahi, Alo, Whi0, Wlo0, Whi1, Wlo1,
      b_ih_l1, b_hh_l1, b_ih_l1r, b_hh_l1r,
      xg, xg + (size_t)M_ * NG, M_, NG, 1024);
  lstm_layer<<<32, 512, 0, stream>>>(w_hh_l1, w_hh_l1r, xg, h_ex,
                                     outb, nullptr, nullptr,
                                     flags + (size_t)2 * FLAG_T * 16);
  // ---- attention pooling ----
  attn_pool<<<16, 256, 0, stream>>>(outb, attn_w, attn_b, enc);
}

// Round 3
// 12659.738 us; speedup vs baseline: 1.0553x; 1.0553x over previous
//
#include <hip/hip_runtime.h>
#include <hip/hip_bf16.h>
#include <cstdio>

typedef unsigned short ushort_t;
typedef __attribute__((ext_vector_type(4))) float f32x4;
typedef __attribute__((ext_vector_type(4))) unsigned int u32x4;
typedef __attribute__((ext_vector_type(8))) __bf16 bf16x8;
typedef __attribute__((ext_vector_type(8))) unsigned short u16x8;
typedef __attribute__((ext_vector_type(4))) unsigned short u16x4;

#define B_  16
#define T_  1024
#define H_  512
#define NG  2048          // 4*H
#define M_  (B_*T_)       // 16384
#define NBLK_DIR 16       // lstm blocks per direction
#define CNT_STRIDE 1088   // padded per-(layer,dir) counter rows (T_+1 used)

__device__ inline unsigned short f2bf_rne(float f){
  union { float f; unsigned int u; } v; v.f = f;
  unsigned int u = v.u;
  unsigned int r = (u + 0x7fffu + ((u >> 16) & 1u)) >> 16;
  return (unsigned short)r;
}
__device__ inline float bf2f(unsigned short s){
  union { unsigned int u; float f; } v; v.u = ((unsigned int)s) << 16;
  return v.f;
}

__global__ void zero_u32(unsigned* __restrict__ p, int n){
  int i = blockIdx.x * blockDim.x + threadIdx.x;
  if (i < n) p[i] = 0u;
}

// ---------------- split f32 -> bf16 hi + bf16 lo ----------------
__global__ void split_f32_bf16(const float* __restrict__ src,
                               ushort_t* __restrict__ hi, ushort_t* __restrict__ lo,
                               int n4){
  int i = blockIdx.x * blockDim.x + threadIdx.x;
  int stride = gridDim.x * blockDim.x;
  for (; i < n4; i += stride){
    f32x4 v = ((const f32x4*)src)[i];
    u16x4 h4, l4;
    #pragma unroll
    for (int j = 0; j < 4; j++){
      unsigned short h = f2bf_rne(v[j]);
      h4[j] = h;
      l4[j] = f2bf_rne(v[j] - bf2f(h));
    }
    ((u16x4*)hi)[i] = h4;
    ((u16x4*)lo)[i] = l4;
  }
}

// ---------------- split-bf16 MFMA GEMM: C = A * B^T + bias ----------------
__global__ __launch_bounds__(256) void gemm_xg(
    const ushort_t* __restrict__ Ahi, const ushort_t* __restrict__ Alo,
    const ushort_t* __restrict__ Bhi0, const ushort_t* __restrict__ Blo0,
    const ushort_t* __restrict__ Bhi1, const ushort_t* __restrict__ Blo1,
    const float* __restrict__ bi0, const float* __restrict__ bh0,
    const float* __restrict__ bi1, const float* __restrict__ bh1,
    float* __restrict__ C0, float* __restrict__ C1,
    int M, int N, int K)
{
  __shared__ ushort_t As[128*32];
  __shared__ ushort_t Bs[128*32];
  const int tid  = threadIdx.x;
  const int wave = tid >> 6, lane = tid & 63;
  const int l15 = lane & 15, l4 = lane >> 4;
  const int wr = wave >> 1, wc = wave & 1;
  const int n0 = blockIdx.x * 128, m0 = blockIdx.y * 128;
  const int dir = blockIdx.z;
  const ushort_t* Bhi = dir ? Bhi1 : Bhi0;
  const ushort_t* Blo = dir ? Blo1 : Blo0;
  const float* bia = dir ? bi1 : bi0;
  const float* bib = dir ? bh1 : bh0;
  float* C = dir ? C1 : C0;

  f32x4 acc[4][4];
  #pragma unroll
  for (int i = 0; i < 4; i++)
    #pragma unroll
    for (int j = 0; j < 4; j++) acc[i][j] = (f32x4){0.f,0.f,0.f,0.f};

  const int e0 = tid, e1 = 256 + tid;
  const int row0 = e0 >> 2, c80 = (e0 & 3) * 8;
  const int row1 = e1 >> 2, c81 = (e1 & 3) * 8;

  for (int seg = 0; seg < 3; ++seg){
    const ushort_t* Ap = (seg == 2) ? Alo : Ahi;
    const ushort_t* Bp = (seg == 1) ? Blo : Bhi;
    for (int kt = 0; kt < K; kt += 32){
      // async global->LDS staging, width 16 (dst = wave-uniform base + lane*16)
      __builtin_amdgcn_global_load_lds(
        (const __attribute__((address_space(1))) unsigned int*)(Ap + (size_t)(m0 + row0) * K + kt + c80),
        (__attribute__((address_space(3))) unsigned int*)(As + e0 * 8), 16, 0, 0);
      __builtin_amdgcn_global_load_lds(
        (const __attribute__((address_space(1))) unsigned int*)(Bp + (size_t)(n0 + row0) * K + kt + c80),
        (__attribute__((address_space(3))) unsigned int*)(Bs + e0 * 8), 16, 0, 0);
      __builtin_amdgcn_global_load_lds(
        (const __attribute__((address_space(1))) unsigned int*)(Ap + (size_t)(m0 + row1) * K + kt + c81),
        (__attribute__((address_space(3))) unsigned int*)(As + e1 * 8), 16, 0, 0);
      __builtin_amdgcn_global_load_lds(
        (const __attribute__((address_space(1))) unsigned int*)(Bp + (size_t)(n0 + row1) * K + kt + c81),
        (__attribute__((address_space(3))) unsigned int*)(Bs + e1 * 8), 16, 0, 0);
      __syncthreads();
      bf16x8 af[4], bfr[4];
      #pragma unroll
      for (int m = 0; m < 4; m++)
        af[m] = *(const bf16x8*)(As + (wr*64 + m*16 + l15) * 32 + l4 * 8);
      #pragma unroll
      for (int n = 0; n < 4; n++)
        bfr[n] = *(const bf16x8*)(Bs + (wc*64 + n*16 + l15) * 32 + l4 * 8);
      #pragma unroll
      for (int m = 0; m < 4; m++)
        #pragma unroll
        for (int n = 0; n < 4; n++)
          acc[m][n] = __builtin_amdgcn_mfma_f32_16x16x32_bf16(af[m], bfr[n], acc[m][n], 0, 0, 0);
      __syncthreads();
    }
  }
  #pragma unroll
  for (int m = 0; m < 4; m++)
    #pragma unroll
    for (int n = 0; n < 4; n++){
      int col = n0 + wc*64 + n*16 + l15;
      float bias = bia[col] + bib[col];
      #pragma unroll
      for (int r = 0; r < 4; r++){
        int row = m0 + wr*64 + m*16 + l4*4 + r;
        C[(size_t)row * N + col] = acc[m][n][r] + bias;
      }
    }
}

// ---------------- persistent bidirectional LSTM layer (LLC handshake) ----------------
// 32 blocks x 512 threads. Block = (dir = blk>>4, cb = blk&15), owns h-cols [32*cb, 32*cb+32).
// Wave = (gate = w>>1, colhalf = w&1). W_hh split-bf16 in registers.
// h exchange: packed (hh|hl<<16) u32 per col, agent-scope relaxed atomics (sc1, through LLC);
// per-step agent atomicAdd counter; NO threadfence (no L2 wb/inv on critical path).
__global__ __launch_bounds__(512, 1) void lstm_layer(
    const float* __restrict__ whh_fwd, const float* __restrict__ whh_bwd,
    const float* __restrict__ xg,      // [2][M_][NG], m = b*T + t
    unsigned* __restrict__ h_pack,     // [2 dir][2 buf][16][512] u32
    unsigned* __restrict__ cnt,        // [2 dir][CNT_STRIDE]
    float* __restrict__ out_f32,       // [B][T][1024] or null
    ushort_t* __restrict__ out_hi,     // [B][T][1024] or null (split output)
    ushort_t* __restrict__ out_lo)
{
  const int dir = blockIdx.x >> 4;
  const int cb  = blockIdx.x & 15;
  const int tid = threadIdx.x;
  const int wave = tid >> 6, lane = tid & 63;
  const int gate = wave >> 1, ch = wave & 1;
  const int l15 = lane & 15, l4 = lane >> 4;
  const float* whh = dir ? whh_bwd : whh_fwd;
  unsigned* cn = cnt + (size_t)dir * CNT_STRIDE;
  unsigned* hp = h_pack + (size_t)dir * 2 * 8192;   // [2 buf][16][512]

  // LDS h tile in MFMA-fragment order: u32 slot = ((s*4+l4)*16 + row)*4 + jp
  __shared__ ushort_t hfhi[8192];
  __shared__ ushort_t hflo[8192];
  __shared__ float gbuf[4][16][33];

  // --- W_hh fragments (split bf16): wave rows gate*512 + cb*32 + ch*16 + l15 ---
  bf16x8 Whi[16], Wlo[16];
  {
    const int wrow = gate * 512 + cb * 32 + ch * 16 + l15;
    const float* p0 = whh + (size_t)wrow * 512;
    #pragma unroll
    for (int s = 0; s < 16; s++){
      const float* p = p0 + s * 32 + l4 * 8;
      f32x4 va = *(const f32x4*)(p);
      f32x4 vb = *(const f32x4*)(p + 4);
      u16x8 th, tl;
      #pragma unroll
      for (int j = 0; j < 4; j++){
        unsigned short h = f2bf_rne(va[j]);
        th[j] = h; tl[j] = f2bf_rne(va[j] - bf2f(h));
        unsigned short h2 = f2bf_rne(vb[j]);
        th[4+j] = h2; tl[4+j] = f2bf_rne(vb[j] - bf2f(h2));
      }
      Whi[s] = __builtin_bit_cast(bf16x8, th);
      Wlo[s] = __builtin_bit_cast(bf16x8, tl);
    }
  }

  const int eb = tid >> 5, ecl = tid & 31, ecol = cb * 32 + ecl;

  // --- zero own h0 slice (buf 0), publish cnt[0] ---
  __hip_atomic_store(&hp[eb * 512 + ecol], 0u, __ATOMIC_RELAXED, __HIP_MEMORY_SCOPE_AGENT);
  asm volatile("s_waitcnt vmcnt(0)" ::: "memory");
  __syncthreads();
  if (tid == 0)
    __hip_atomic_fetch_add(&cn[0], 1u, __ATOMIC_RELAXED, __HIP_MEMORY_SCOPE_AGENT);

  float c_state = 0.0f;

  for (int t = 0; t < T_; ++t){
    // A) prefetch xg for this step (HBM latency hides under the poll)
    const int t_eff = dir ? (T_ - 1 - t) : t;
    const float* xgp = xg + ((size_t)dir * M_ + (size_t)eb * T_ + t_eff) * NG + ecol;
    float xi = xgp[0];
    float xf = xgp[512];
    float xgg = xgp[1024];
    float xo = xgp[1536];

    // B) wait for all 16 producer slices of h_t
    if (tid == 0){
      while (__hip_atomic_load(&cn[t], __ATOMIC_RELAXED, __HIP_MEMORY_SCOPE_AGENT) < (unsigned)NBLK_DIR)
        __builtin_amdgcn_s_sleep(1);
    }
    __syncthreads();

    // C) stage h_t from LLC into LDS (fragment-order; slot-linear writes)
    {
      unsigned long long* src64 = (unsigned long long*)(hp + (t & 1) * 8192);
      #pragma unroll
      for (int i = 0; i < 8; i++){
        int slot = i * 512 + tid;              // u32 slot 0..4095
        int sl4 = slot >> 6;                   // s*4 + l4
        int row = (slot >> 2) & 15;
        int jp  = slot & 3;
        int chalf = (sl4 >> 2) * 16 + (sl4 & 3) * 4 + jp;   // c/2
        unsigned long long v = __hip_atomic_load(&src64[row * 256 + chalf],
                                                 __ATOMIC_RELAXED, __HIP_MEMORY_SCOPE_AGENT);
        unsigned hh2 = (unsigned)(v & 0xffffu) | ((unsigned)((v >> 32) & 0xffffu) << 16);
        unsigned hl2 = (unsigned)((v >> 16) & 0xffffu) | ((unsigned)((v >> 48) & 0xffffu) << 16);
        ((unsigned*)hfhi)[slot] = hh2;
        ((unsigned*)hflo)[slot] = hl2;
      }
    }
    __syncthreads();

    // D) gates: 3 independent MFMA chains (hi*Whi, hi*Wlo, lo*Whi)
    {
      f32x4 a0 = {0.f,0.f,0.f,0.f}, a1 = a0, a2 = a0;
      #pragma unroll
      for (int s = 0; s < 16; s++){
        bf16x8 ah = *(const bf16x8*)&hfhi[(s * 64 + l4 * 16 + l15) * 8];
        bf16x8 al = *(const bf16x8*)&hflo[(s * 64 + l4 * 16 + l15) * 8];
        a0 = __builtin_amdgcn_mfma_f32_16x16x32_bf16(ah, Whi[s], a0, 0, 0, 0);
        a1 = __builtin_amdgcn_mfma_f32_16x16x32_bf16(ah, Wlo[s], a1, 0, 0, 0);
        a2 = __builtin_amdgcn_mfma_f32_16x16x32_bf16(al, Whi[s], a2, 0, 0, 0);
      }
      f32x4 acc = a0 + a1;
      acc = acc + a2;
      #pragma unroll
      for (int r = 0; r < 4; r++)
        gbuf[gate][l4 * 4 + r][ch * 16 + l15] = acc[r];
    }
    __syncthreads();

    // E) elementwise LSTM cell + h publish store
    float h, hh_f, hl_f;
    unsigned short hh, hl;
    size_t oidx;
    {
      float pi = gbuf[0][eb][ecl] + xi;
      float pf = gbuf[1][eb][ecl] + xf;
      float pg = gbuf[2][eb][ecl] + xgg;
      float po = gbuf[3][eb][ecl] + xo;
      float ig = 1.0f / (1.0f + __expf(-pi));
      float fg = 1.0f / (1.0f + __expf(-pf));
      float gg = tanhf(pg);
      float og = 1.0f / (1.0f + __expf(-po));
      c_state = fg * c_state + ig * gg;
      h = og * tanhf(c_state);
      hh = f2bf_rne(h);
      hl = f2bf_rne(h - bf2f(hh));
      oidx = ((size_t)eb * T_ + t_eff) * 1024 + dir * 512 + ecol;
      __hip_atomic_store(&hp[((t + 1) & 1) * 8192 + eb * 512 + ecol],
                         (unsigned)hh | ((unsigned)hl << 16),
                         __ATOMIC_RELAXED, __HIP_MEMORY_SCOPE_AGENT);
    }
    asm volatile("s_waitcnt vmcnt(0)" ::: "memory");
    __syncthreads();

    // F) publish step t+1
    if (tid == 0)
      __hip_atomic_fetch_add(&cn[t + 1], 1u, __ATOMIC_RELAXED, __HIP_MEMORY_SCOPE_AGENT);

    // G) output stores (off critical path)
    if (out_f32) out_f32[oidx] = h;
    if (out_hi){ out_hi[oidx] = hh; out_lo[oidx] = hl; }
  }
}

// ---------------- attention pooling ----------------
__device__ inline float dot4(f32x4 a, f32x4 b){
  return a[0]*b[0] + a[1]*b[1] + a[2]*b[2] + a[3]*b[3];
}

__global__ __launch_bounds__(256) void attn_pool(
    const float* __restrict__ out1,   // [B][T][1024]
    const float* __restrict__ aw,     // [1024]
    const float* __restrict__ ab,     // [1]
    float* __restrict__ enc)          // [B][1024]
{
  __shared__ float wbuf[1024];
  __shared__ float sc[1024];
  __shared__ float red[16];
  const int b = blockIdx.x;
  const int tid = threadIdx.x;
  const int wave = tid >> 6, lane = tid & 63;
  ((f32x4*)wbuf)[tid] = ((const f32x4*)aw)[tid];
  __syncthreads();
  const float* ob = out1 + (size_t)b * T_ * 1024;
  const float bias = ab[0];

  for (int t = wave; t < T_; t += 4){
    const float* row = ob + (size_t)t * 1024;
    float s = dot4(((const f32x4*)row)[lane],       ((const f32x4*)wbuf)[lane])
            + dot4(((const f32x4*)row)[lane + 64],  ((const f32x4*)wbuf)[lane + 64])
            + dot4(((const f32x4*)row)[lane + 128], ((const f32x4*)wbuf)[lane + 128])
            + dot4(((const f32x4*)row)[lane + 192], ((const f32x4*)wbuf)[lane + 192]);
    #pragma unroll
    for (int o = 32; o > 0; o >>= 1) s += __shfl_xor(s, o, 64);
    if (lane == 0) sc[t] = s + bias;
  }
  __syncthreads();

  float m = -1e30f;
  for (int i = tid; i < 1024; i += 256) m = fmaxf(m, sc[i]);
  #pragma unroll
  for (int o = 32; o > 0; o >>= 1) m = fmaxf(m, __shfl_xor(m, o, 64));
  if (lane == 0) red[wave] = m;
  __syncthreads();
  m = fmaxf(fmaxf(red[0], red[1]), fmaxf(red[2], red[3]));

  float ssum = 0.f;
  for (int i = tid; i < 1024; i += 256){
    float p = __expf(sc[i] - m);
    sc[i] = p;
    ssum += p;
  }
  #pragma unroll
  for (int o = 32; o > 0; o >>= 1) ssum += __shfl_xor(ssum, o, 64);
  if (lane == 0) red[8 + wave] = ssum;
  __syncthreads();
  float inv = 1.0f / (red[8] + red[9] + red[10] + red[11]);

  f32x4 a = {0.f,0.f,0.f,0.f};
  for (int t = 0; t < T_; t++){
    f32x4 v = *(const f32x4*)(ob + (size_t)t * 1024 + tid * 4);
    float p = sc[t];
    a[0] += p * v[0]; a[1] += p * v[1]; a[2] += p * v[2]; a[3] += p * v[3];
  }
  f32x4 r = { a[0]*inv, a[1]*inv, a[2]*inv, a[3]*inv };
  *(f32x4*)(enc + (size_t)b * 1024 + tid * 4) = r;
}

// ---------------- host ----------------
extern "C" void kernel_launch(void* const* d_in, const int* in_sizes, int n_in,
                              void* d_out, int out_size, void* d_ws, size_t ws_size,
                              hipStream_t stream)
{
  const float* x        = (const float*)d_in[0];
  const float* w_ih_l0  = (const float*)d_in[1];
  const float* w_hh_l0  = (const float*)d_in[2];
  const float* b_ih_l0  = (const float*)d_in[3];
  const float* b_hh_l0  = (const float*)d_in[4];
  const float* w_ih_l0r = (const float*)d_in[5];
  const float* w_hh_l0r = (const float*)d_in[6];
  const float* b_ih_l0r = (const float*)d_in[7];
  const float* b_hh_l0r = (const float*)d_in[8];
  const float* w_ih_l1  = (const float*)d_in[9];
  const float* w_hh_l1  = (const float*)d_in[10];
  const float* b_ih_l1  = (const float*)d_in[11];
  const float* b_hh_l1  = (const float*)d_in[12];
  const float* w_ih_l1r = (const float*)d_in[13];
  const float* w_hh_l1r = (const float*)d_in[14];
  const float* b_ih_l1r = (const float*)d_in[15];
  const float* b_hh_l1r = (const float*)d_in[16];
  const float* attn_w   = (const float*)d_in[17];
  const float* attn_b   = (const float*)d_in[18];
  float* enc = (float*)d_out;

  char* ws = (char*)d_ws;
  size_t off = 0;
  auto alloc = [&](size_t bytes) -> void* {
    void* p = ws + off;
    off += (bytes + 255) & ~(size_t)255;
    return p;
  };
  ushort_t* Ahi  = (ushort_t*)alloc((size_t)M_ * 2048 * 2);
  ushort_t* Alo  = (ushort_t*)alloc((size_t)M_ * 2048 * 2);
  ushort_t* Whi0 = (ushort_t*)alloc((size_t)2048 * 2048 * 2);
  ushort_t* Wlo0 = (ushort_t*)alloc((size_t)2048 * 2048 * 2);
  ushort_t* Whi1 = (ushort_t*)alloc((size_t)2048 * 2048 * 2);
  ushort_t* Wlo1 = (ushort_t*)alloc((size_t)2048 * 2048 * 2);
  float*    xg   = (float*)alloc((size_t)2 * M_ * NG * 4);
  float*    outb = (float*)alloc((size_t)M_ * 1024 * 4);
  unsigned* h_pack = (unsigned*)alloc((size_t)2 * 2 * 16 * 512 * 4);
  unsigned* cnt    = (unsigned*)alloc((size_t)2 * 2 * CNT_STRIDE * 4);  // [layer][dir][..]
  if (off > ws_size){
    fprintf(stderr, "kernel_launch: workspace too small: need %zu have %zu\n", off, ws_size);
    return;
  }

  // zero step counters (monotonic handshake state) every call — replay-deterministic
  {
    int n = 2 * 2 * CNT_STRIDE;
    zero_u32<<<(n + 255) / 256, 256, 0, stream>>>(cnt, n);
  }

  // ---- layer 0 ----
  split_f32_bf16<<<2048, 256, 0, stream>>>(x, Ahi, Alo, M_ * 2048 / 4);
  split_f32_bf16<<<512, 256, 0, stream>>>(w_ih_l0,  Whi0, Wlo0, 2048 * 2048 / 4);
  split_f32_bf16<<<512, 256, 0, stream>>>(w_ih_l0r, Whi1, Wlo1, 2048 * 2048 / 4);
  gemm_xg<<<dim3(16, 128, 2), 256, 0, stream>>>(
      Ahi, Alo, Whi0, Wlo0, Whi1, Wlo1,
      b_ih_l0, b_hh_l0, b_ih_l0r, b_hh_l0r,
      xg, xg + (size_t)M_ * NG, M_, NG, 2048);
  // LSTM layer 0: writes split-bf16 output directly into Ahi/Alo (x splits dead now)
  lstm_layer<<<32, 512, 0, stream>>>(w_hh_l0, w_hh_l0r, xg, h_pack, cnt,
                                     nullptr, Ahi, Alo);
  // ---- layer 1 ----
  split_f32_bf16<<<512, 256, 0, stream>>>(w_ih_l1,  Whi0, Wlo0, 2048 * 1024 / 4);
  split_f32_bf16<<<512, 256, 0, stream>>>(w_ih_l1r, Whi1, Wlo1, 2048 * 1024 / 4);
  gemm_xg<<<dim3(16, 128, 2), 256, 0, stream>>>(
      Ahi, Alo, Whi0, Wlo0, Whi1, Wlo1,
      b_ih_l1, b_hh_l1, b_ih_l1r, b_hh_l1r,
      xg, xg + (size_t)M_ * NG, M_, NG, 1024);
  lstm_layer<<<32, 512, 0, stream>>>(w_hh_l1, w_hh_l1r, xg, h_pack,
                                     cnt + (size_t)2 * CNT_STRIDE,
                                     outb, nullptr, nullptr);
  // ---- attention pooling ----
  attn_pool<<<16, 256, 0, stream>>>(outb, attn_w, attn_b, enc);
}